// Round 15
// baseline (105.867 us; speedup 1.0000x reference)
//
#include <hip/hip_runtime.h>
#include <math.h>

#define B_N   8192
#define D_K   256
#define NGENE 200
#define MAXN  512

typedef short  bf16x8 __attribute__((ext_vector_type(8)));
typedef float  f32x4  __attribute__((ext_vector_type(4)));

// ---- workspace layout (bytes), total 4,759,552 (proven size) ----
#define OFF_FNBF    0u          // 8192*256*2 = 4194304
#define OFF_LPART   4194304u    // bf16 [32][8192] = 524288
#define OFF_HIST    4718592u    // 256*4
#define OFF_OFFS    4719616u    // 256*4
#define OFF_SORTED  4720640u    // 8192*4
#define OFF_CROSSP  4753408u    // 528*4 (pad region 4096)
#define OFF_WITHINP 4757504u    // 256*4
#define OFF_CCORR   4758528u    // 256*4  -> end 4759552

__device__ __forceinline__ unsigned short f2bf(float f) {
    unsigned int u = __float_as_uint(f);
    unsigned int r = u + 0x7fffu + ((u >> 16) & 1u);
    return (unsigned short)(r >> 16);
}
__device__ __forceinline__ float bf2fu(unsigned short h) { return __uint_as_float(((unsigned int)h) << 16); }
__device__ __forceinline__ float bf2f_lo(unsigned int u) { return __uint_as_float(u << 16); }
__device__ __forceinline__ float bf2f_hi(unsigned int u) { return __uint_as_float(u & 0xffff0000u); }

// ---- kernel 1: normalize (blocks 0..2047) + hist/prefix/scatter (block 2048) ----
__global__ __launch_bounds__(256) void k_np(const float* __restrict__ feat,
                                            const int* __restrict__ lab,
                                            unsigned short* __restrict__ fnbf,
                                            int* __restrict__ hist,
                                            int* __restrict__ offs,
                                            int* __restrict__ sorted) {
    if (blockIdx.x < 2048) {
        int wave = threadIdx.x >> 6, lane = threadIdx.x & 63;
        int row  = blockIdx.x * 4 + wave;
        const float4* src = reinterpret_cast<const float4*>(feat + (size_t)row * D_K);
        float4 v = src[lane];
        float ss = v.x * v.x + v.y * v.y + v.z * v.z + v.w * v.w;
#pragma unroll
        for (int m = 1; m < 64; m <<= 1) ss += __shfl_xor(ss, m);
        float rn = 1.0f / sqrtf(ss);
        ushort4 o;
        o.x = f2bf(v.x * rn); o.y = f2bf(v.y * rn);
        o.z = f2bf(v.z * rn); o.w = f2bf(v.w * rn);
        reinterpret_cast<ushort4*>(fnbf + (size_t)row * D_K)[lane] = o;
        return;
    }
    __shared__ int sh_hist[256], sh_scan[256], sh_cur[256];
    int t = threadIdx.x;
    sh_hist[t] = 0;
    __syncthreads();
    for (int i = t; i < B_N; i += 256) {
        int lb = lab[i];
        if (lb >= 0 && lb < NGENE) atomicAdd(&sh_hist[lb], 1);
    }
    __syncthreads();
    int v = sh_hist[t];
    sh_scan[t] = v;
    __syncthreads();
#pragma unroll
    for (int d = 1; d < 256; d <<= 1) {
        int x = (t >= d) ? sh_scan[t - d] : 0;
        __syncthreads();
        sh_scan[t] += x;
        __syncthreads();
    }
    int excl = sh_scan[t] - v;
    sh_cur[t] = excl;
    if (t < NGENE) { hist[t] = v; offs[t] = excl; }
    __syncthreads();
    for (int i = t; i < B_N; i += 256) {
        int lb = lab[i];
        if (lb >= 0 && lb < NGENE) {
            int pos = atomicAdd(&sh_cur[lb], 1);
            sorted[pos] = i;
        }
    }
}

// asm-pinned A-fragment loads (compiler cannot rematerialize or sink)
#define GLOAD8(arr, vo) do {                                                                   \
    asm volatile("global_load_dwordx4 %0, %1, %2 offset:0"   : "=v"(arr[0]) : "v"(vo), "s"(fb)); \
    asm volatile("global_load_dwordx4 %0, %1, %2 offset:64"  : "=v"(arr[1]) : "v"(vo), "s"(fb)); \
    asm volatile("global_load_dwordx4 %0, %1, %2 offset:128" : "=v"(arr[2]) : "v"(vo), "s"(fb)); \
    asm volatile("global_load_dwordx4 %0, %1, %2 offset:192" : "=v"(arr[3]) : "v"(vo), "s"(fb)); \
    asm volatile("global_load_dwordx4 %0, %1, %2 offset:256" : "=v"(arr[4]) : "v"(vo), "s"(fb)); \
    asm volatile("global_load_dwordx4 %0, %1, %2 offset:320" : "=v"(arr[5]) : "v"(vo), "s"(fb)); \
    asm volatile("global_load_dwordx4 %0, %1, %2 offset:384" : "=v"(arr[6]) : "v"(vo), "s"(fb)); \
    asm volatile("global_load_dwordx4 %0, %1, %2 offset:448" : "=v"(arr[7]) : "v"(vo), "s"(fb)); \
} while (0)

// async global->LDS, 16B per lane, zero VGPR result cost
#define GL_LDS16(gp, lp)                                                          \
    __builtin_amdgcn_global_load_lds(                                             \
        (const __attribute__((address_space(1))) unsigned int*)(gp),              \
        (__attribute__((address_space(3))) unsigned int*)(lp), 16, 0, 0)

#define Z4 ((f32x4){0.f, 0.f, 0.f, 0.f})
#define MFMA(A, B, C) __builtin_amdgcn_mfma_f32_16x16x32_bf16(A, B, C, 0, 0, 0)

// epilogue with column-sum capture: exp into row-sum LS, col-partial CE, relu CS
#define EPI2(AC, LS, CE, CS) do {                               \
    _Pragma("unroll")                                           \
    for (int r = 0; r < 4; ++r) {                               \
        float av = AC[r];                                       \
        float e = __expf(2.0f * av);                            \
        LS[r] += e; CE += e;                                    \
        CS += fmaxf(av - 0.05f, 0.f);                           \
    }                                                           \
} while (0)

#define WAIT_VM(n) do { asm volatile("s_waitcnt vmcnt(" #n ")" ::: "memory"); \
                        __builtin_amdgcn_sched_barrier(0); } while (0)

// stage 32-col tile ST into LDS buffer BUF (4 x 1KB issues per wave)
#define STAGE4(BUF, ST) do {                                                       \
    const char* gsb = gw + (unsigned)(ST) * 16384u;                                \
    GL_LDS16(gsb + sv[0], smem_c + (BUF) + sd[0]);                                 \
    GL_LDS16(gsb + sv[1], smem_c + (BUF) + sd[1]);                                 \
    GL_LDS16(gsb + sv[2], smem_c + (BUF) + sd[2]);                                 \
    GL_LDS16(gsb + sv[3], smem_c + (BUF) + sd[3]);                                 \
} while (0)

// ---- kernel 2: SYMMETRIC fused pairwise pass over upper-triangle 256x256 blocks ----
// 528 blocks (rg <= cw). Row-sums -> l_part[cw][rows]; col-sums (mirror) -> l_part[rg][cols].
// Off-diagonal relu partials count double. Unmasked sums; corrections in k_within.
__global__ __launch_bounds__(256, 2) void k_pairwise(const unsigned short* __restrict__ fnbf,
                                                     unsigned short* __restrict__ l_part,
                                                     float* __restrict__ cross_part) {
    __shared__ __align__(16) char smem_c[32768];   // 2 x 16KB B tile ping-pong
    __shared__ float colsumws[1024];               // [wave][256] col partials
    __shared__ float shc[4];

    int tid = threadIdx.x;
    int wave = tid >> 6, lane = tid & 63;
    int g16 = lane >> 4, l16 = lane & 15;
    int l7 = l16 & 7;

    // upper-triangle decode: b -> (rg, cw), rg <= cw
    int b = blockIdx.x, rg = 0, rem = b;
    while (rem >= 32 - rg) { rem -= 32 - rg; ++rg; }
    int cw = rg + rem;
    bool offd = (rg != cw);

    int r0 = rg * 256 + wave * 64;
    const unsigned short* fb = fnbf;

    // zero own colsum slice (wave-private; no barrier needed)
#pragma unroll
    for (int k2 = 0; k2 < 4; ++k2) colsumws[wave * 256 + lane * 4 + k2] = 0.f;

    // A fragments pinned: 4 row-tiles x 8 k-slices = 128 VGPRs
    bf16x8 a0[8], a1[8], a2[8], a3[8];
    unsigned voa = (unsigned)(r0 + l16) * 512u + (unsigned)g16 * 16u;
    GLOAD8(a0, voa); voa += 8192u;
    GLOAD8(a1, voa); voa += 8192u;
    GLOAD8(a2, voa); voa += 8192u;
    GLOAD8(a3, voa);

    // staging: tile = 32 cols x 512B; LDS slot f = col*32 + s holds source chunk
    // s ^ (col&7) (inverse swizzle on source, linear LDS dest). f = wave*256+q*64+lane.
    const char* gw = (const char*)fnbf + (size_t)cw * 131072u;
    unsigned sv[4], sd[4];
#pragma unroll
    for (int q = 0; q < 4; ++q) {
        int f = wave * 256 + q * 64 + lane;
        int col = f >> 5;
        sv[q] = (unsigned)(col * 512 + (((f & 31) ^ (col & 7)) << 4));
        sd[q] = (unsigned)(f << 4);
    }

    // prologue: stage tile 0 into buf0 (A loads + tile0 drain at first WAIT)
    STAGE4(0u, 0);

    float lsum[4][4] = {};
    float cs0 = 0.f, cs1 = 0.f, cs2 = 0.f, cs3 = 0.f;
    int vb = l16 * 512;

#pragma unroll 1
    for (int st = 0; st < 8; ++st) {
        WAIT_VM(0);
        __builtin_amdgcn_s_barrier();
        if (st < 7) STAGE4((unsigned)(((st + 1) & 1) << 14), st + 1);

        const char* base = smem_c + ((st & 1) << 14);
        f32x4 acA0 = Z4, acA1 = Z4, acA2 = Z4, acA3 = Z4;
        f32x4 acB0 = Z4, acB1 = Z4, acB2 = Z4, acB3 = Z4;
#pragma unroll
        for (int ks = 0; ks < 8; ++ks) {
            const char* p = base + (unsigned)(vb + ((((ks << 2) | g16) ^ l7) << 4));
            bf16x8 bv0 = *(const bf16x8*)p;
            bf16x8 bv1 = *(const bf16x8*)(p + 8192);
            acA0 = MFMA(a0[ks], bv0, acA0);
            acA1 = MFMA(a1[ks], bv0, acA1);
            acA2 = MFMA(a2[ks], bv0, acA2);
            acA3 = MFMA(a3[ks], bv0, acA3);
            acB0 = MFMA(a0[ks], bv1, acB0);
            acB1 = MFMA(a1[ks], bv1, acB1);
            acB2 = MFMA(a2[ks], bv1, acB2);
            acB3 = MFMA(a3[ks], bv1, acB3);
        }
        float ceA = 0.f, ceB = 0.f;
        EPI2(acA0, lsum[0], ceA, cs0); EPI2(acA1, lsum[1], ceA, cs1);
        EPI2(acA2, lsum[2], ceA, cs2); EPI2(acA3, lsum[3], ceA, cs3);
        EPI2(acB0, lsum[0], ceB, cs0); EPI2(acB1, lsum[1], ceB, cs1);
        EPI2(acB2, lsum[2], ceB, cs2); EPI2(acB3, lsum[3], ceB, cs3);

        if (offd) {
            // reduce col partials over the 4 g16 lane-groups (rows of this wave)
            ceA += __shfl_xor(ceA, 16); ceA += __shfl_xor(ceA, 32);
            ceB += __shfl_xor(ceB, 16); ceB += __shfl_xor(ceB, 32);
            if (g16 == 0) {
                colsumws[wave * 256 + st * 32 + l16]      += ceA;
                colsumws[wave * 256 + st * 32 + 16 + l16] += ceB;
            }
        }
    }

    // row sums -> l_part[cw][row]
#pragma unroll
    for (int t = 0; t < 4; ++t)
#pragma unroll
        for (int r = 0; r < 4; ++r) {
            float v = lsum[t][r];
            v += __shfl_xor(v, 1); v += __shfl_xor(v, 2);
            v += __shfl_xor(v, 4); v += __shfl_xor(v, 8);
            if (l16 == 0)
                l_part[(size_t)cw * B_N + r0 + t * 16 + g16 * 4 + r] = f2bf(v);
        }

    __syncthreads();   // all waves' colsum partials visible

    // col sums (mirror rows) -> l_part[rg][cw*256 + col], off-diagonal only
    if (offd) {
        float cs = colsumws[tid] + colsumws[256 + tid] + colsumws[512 + tid] + colsumws[768 + tid];
        l_part[(size_t)rg * B_N + cw * 256 + tid] = f2bf(cs);
    }

    // block-reduce half-relu sum; off-diagonal counts both orders
    float c = (cs0 + cs1) + (cs2 + cs3);
#pragma unroll
    for (int m = 1; m < 64; m <<= 1) c += __shfl_xor(c, m);
    if (lane == 0) shc[wave] = c;
    __syncthreads();
    if (tid == 0) {
        float tot = shc[0] + shc[1] + shc[2] + shc[3];
        cross_part[b] = offd ? 2.0f * tot : tot;
    }
}

// full-row dot from global (fallback path only; 32 x 16B = 512B per row)
__device__ __forceinline__ float dot_g(const uint4* __restrict__ fu, int i, int j) {
    const uint4* pa = fu + (size_t)i * 32;
    const uint4* pb = fu + (size_t)j * 32;
    float d = 0.f;
#pragma unroll
    for (int k = 0; k < 32; ++k) {
        uint4 ua = pa[k], ub = pb[k];
        d = fmaf(bf2f_lo(ua.x), bf2f_lo(ub.x), d);
        d = fmaf(bf2f_hi(ua.x), bf2f_hi(ub.x), d);
        d = fmaf(bf2f_lo(ua.y), bf2f_lo(ub.y), d);
        d = fmaf(bf2f_hi(ua.y), bf2f_hi(ub.y), d);
        d = fmaf(bf2f_lo(ua.z), bf2f_lo(ub.z), d);
        d = fmaf(bf2f_hi(ua.z), bf2f_hi(ub.z), d);
        d = fmaf(bf2f_lo(ua.w), bf2f_lo(ub.w), d);
        d = fmaf(bf2f_hi(ua.w), bf2f_hi(ub.w), d);
    }
    return d;
}

// ---- kernel 3: per-gene Gram matrix via MFMA + corrections + within loss ----
__global__ __launch_bounds__(256) void k_within(const unsigned short* __restrict__ fnbf,
                                                const int* __restrict__ hist,
                                                const int* __restrict__ offs,
                                                const int* __restrict__ sorted,
                                                const unsigned short* __restrict__ l_part,
                                                float* __restrict__ within_part,
                                                float* __restrict__ cross_corr) {
    int g = blockIdx.x;
    int n = hist[g], start = offs[g];
    int t = threadIdx.x;
    int wave = t >> 6, lane = t & 63;
    int g16 = lane >> 4, l16 = lane & 15;

    __shared__ float sim[128 * 130];   // sim[i][j] at i*130+j (pad -> 2-way banks)
    __shared__ int   rid[MAXN];
    __shared__ float slse[MAXN];
    __shared__ float red[256];

    for (int idx = t; idx < n; idx += 256) rid[idx] = sorted[start + idx];
    __syncthreads();

    float ccor = 0.f, wsum = 0.f;

    if (n <= 128) {
        int NT = (n + 15) >> 4;
        const bf16x8* fv = reinterpret_cast<const bf16x8*>(fnbf);
        for (int tile = wave; tile < NT * NT; tile += 4) {
            int ti = tile / NT, tj = tile - ti * NT;
            int ia = ti * 16 + l16;
            int ib = tj * 16 + l16;
            int ra = rid[ia < n ? ia : (n - 1)];
            int rb = rid[ib < n ? ib : (n - 1)];
            f32x4 acc = Z4;
#pragma unroll
            for (int ks = 0; ks < 8; ++ks) {
                bf16x8 av = fv[(size_t)ra * 32 + ks * 4 + g16];
                bf16x8 bv = fv[(size_t)rb * 32 + ks * 4 + g16];
                acc = MFMA(av, bv, acc);
            }
            int si = ti * 16 + g16 * 4;
            int sj = tj * 16 + l16;
#pragma unroll
            for (int r = 0; r < 4; ++r)
                sim[(si + r) * 130 + sj] = acc[r];
        }
        __syncthreads();

        for (int i = t; i < n; i += 256) {
            float raw = 0.f;
#pragma unroll
            for (int k = 0; k < 32; ++k) raw += bf2fu(l_part[(size_t)k * B_N + rid[i]]);
            const float* srow = &sim[i * 130];
            float esum = 0.f;
            for (int j = 0; j < n; ++j) {
                float s = 2.0f * srow[j];
                esum += __expf(s);
                ccor += fmaxf(s - 0.1f, 0.f);
            }
            slse[i] = __logf(raw - esum);
        }
        __syncthreads();

        int nn = n * n;
        for (int p = t; p < nn; p += 256) {
            int i = p / n, j = p - i * n;
            if (j <= i) continue;
            float s = 2.0f * sim[i * 130 + j];
            int ai = (rid[i] < rid[j]) ? i : j;
            float x = slse[ai] - s;
            wsum += fmaxf(x, 0.f) + log1pf(__expf(-fabsf(x)));
        }
    } else {
        const uint4* fu = reinterpret_cast<const uint4*>(fnbf);
        for (int i = t; i < n; i += 256) {
            float raw = 0.f;
#pragma unroll
            for (int k = 0; k < 32; ++k) raw += bf2fu(l_part[(size_t)k * B_N + rid[i]]);
            float esum = 0.f;
            for (int j = 0; j < n; ++j) {
                float s = 2.0f * dot_g(fu, rid[i], rid[j]);
                esum += __expf(s);
                ccor += fmaxf(s - 0.1f, 0.f);
            }
            slse[i] = __logf(raw - esum);
        }
        __syncthreads();
        int nn = n * n;
        for (int p = t; p < nn; p += 256) {
            int i = p / n, j = p - i * n;
            if (j <= i) continue;
            float s = 2.0f * dot_g(fu, rid[i], rid[j]);
            int ai = (rid[i] < rid[j]) ? i : j;
            float x = slse[ai] - s;
            wsum += fmaxf(x, 0.f) + log1pf(__expf(-fabsf(x)));
        }
    }

    red[t] = wsum;
    __syncthreads();
#pragma unroll
    for (int d2 = 128; d2 > 0; d2 >>= 1) {
        if (t < d2) red[t] += red[t + d2];
        __syncthreads();
    }
    if (t == 0) within_part[g] = red[0];
    __syncthreads();
    red[t] = ccor;
    __syncthreads();
#pragma unroll
    for (int d2 = 128; d2 > 0; d2 >>= 1) {
        if (t < d2) red[t] += red[t + d2];
        __syncthreads();
    }
    if (t == 0) cross_corr[g] = red[0];
}

// ---- kernel 4: final reduction + outputs ----
__global__ __launch_bounds__(256) void k_finalize(const float* __restrict__ cross_part,
                                                  const float* __restrict__ within_part,
                                                  const float* __restrict__ cross_corr,
                                                  const int* __restrict__ hist,
                                                  float* __restrict__ out) {
    __shared__ float shc[256];
    __shared__ float shw[256];
    __shared__ float shk[256];
    __shared__ long long shs[256];
    int t = threadIdx.x;
    float cs = 0.f;
    for (int i = t; i < 528; i += 256) cs += cross_part[i];
    float wv = 0.f, cc = 0.f;
    long long s2 = 0;
    if (t < NGENE) {
        wv = within_part[t];
        cc = cross_corr[t];
        long long h = hist[t];
        s2 = h * h;
    }
    shc[t] = cs; shw[t] = wv; shk[t] = cc; shs[t] = s2;
    __syncthreads();
#pragma unroll
    for (int d = 128; d > 0; d >>= 1) {
        if (t < d) {
            shc[t] += shc[t + d]; shw[t] += shw[t + d];
            shk[t] += shk[t + d]; shs[t] += shs[t + d];
        }
        __syncthreads();
    }
    if (t == 0) {
        long long S  = shs[0];
        long long nw = S - (long long)B_N;
        long long nc = (long long)B_N * (long long)B_N - S;
        float cross_total = 2.0f * shc[0] - shk[0];   // csum was half-relu units
        float cross_loss = (nc > 0) ? (cross_total / (float)(nc > 1 ? nc : 1)) : 0.f;
        float within     = shw[0];
        out[0] = within + 0.5f * cross_loss;
        out[1] = within;
        out[2] = cross_loss;
        out[3] = (float)nw;
        out[4] = (float)nc;
    }
}

extern "C" void kernel_launch(void* const* d_in, const int* in_sizes, int n_in,
                              void* d_out, int out_size, void* d_ws, size_t ws_size,
                              hipStream_t stream) {
    const float* feat = (const float*)d_in[0];
    const int*   lab  = (const int*)d_in[1];
    float* out = (float*)d_out;
    char* ws = (char*)d_ws;

    unsigned short* fnbf   = (unsigned short*)(ws + OFF_FNBF);
    unsigned short* l_part = (unsigned short*)(ws + OFF_LPART);
    int*   hist            = (int*)(ws + OFF_HIST);
    int*   offs            = (int*)(ws + OFF_OFFS);
    int*   sorted          = (int*)(ws + OFF_SORTED);
    float* cross_part      = (float*)(ws + OFF_CROSSP);
    float* within_part     = (float*)(ws + OFF_WITHINP);
    float* cross_corr      = (float*)(ws + OFF_CCORR);

    k_np<<<2049, 256, 0, stream>>>(feat, lab, fnbf, hist, offs, sorted);
    k_pairwise<<<528, 256, 0, stream>>>(fnbf, l_part, cross_part);
    k_within<<<NGENE, 256, 0, stream>>>(fnbf, hist, offs, sorted, l_part, within_part, cross_corr);
    k_finalize<<<1, 256, 0, stream>>>(cross_part, within_part, cross_corr, hist, out);
}

// Round 16
// 94.431 us; speedup vs baseline: 1.1211x; 1.1211x over previous
//
#include <hip/hip_runtime.h>
#include <math.h>

#define B_N   8192
#define D_K   256
#define NGENE 200
#define MAXN  512

typedef short  bf16x8 __attribute__((ext_vector_type(8)));
typedef float  f32x4  __attribute__((ext_vector_type(4)));

// ---- workspace layout (bytes), total 4,757,504 (proven size) ----
#define OFF_FNBF    0u          // 8192*256*2 = 4194304
#define OFF_LPART   4194304u    // f32 [16][8192] = 524288
#define OFF_HIST    4718592u    // 256*4
#define OFF_OFFS    4719616u    // 256*4
#define OFF_SORTED  4720640u    // 8192*4
#define OFF_CROSSP  4753408u    // 512*4
#define OFF_WITHINP 4755456u    // 256*4
#define OFF_CCORR   4756480u    // 256*4

__device__ __forceinline__ unsigned short f2bf(float f) {
    unsigned int u = __float_as_uint(f);
    unsigned int r = u + 0x7fffu + ((u >> 16) & 1u);
    return (unsigned short)(r >> 16);
}
__device__ __forceinline__ float bf2f_lo(unsigned int u) { return __uint_as_float(u << 16); }
__device__ __forceinline__ float bf2f_hi(unsigned int u) { return __uint_as_float(u & 0xffff0000u); }

// ---- kernel 1: normalize (blocks 0..2047) + hist/prefix/scatter (block 2048) ----
__global__ __launch_bounds__(256) void k_np(const float* __restrict__ feat,
                                            const int* __restrict__ lab,
                                            unsigned short* __restrict__ fnbf,
                                            int* __restrict__ hist,
                                            int* __restrict__ offs,
                                            int* __restrict__ sorted) {
    if (blockIdx.x < 2048) {
        int wave = threadIdx.x >> 6, lane = threadIdx.x & 63;
        int row  = blockIdx.x * 4 + wave;
        const float4* src = reinterpret_cast<const float4*>(feat + (size_t)row * D_K);
        float4 v = src[lane];
        float ss = v.x * v.x + v.y * v.y + v.z * v.z + v.w * v.w;
#pragma unroll
        for (int m = 1; m < 64; m <<= 1) ss += __shfl_xor(ss, m);
        float rn = 1.0f / sqrtf(ss);
        ushort4 o;
        o.x = f2bf(v.x * rn); o.y = f2bf(v.y * rn);
        o.z = f2bf(v.z * rn); o.w = f2bf(v.w * rn);
        reinterpret_cast<ushort4*>(fnbf + (size_t)row * D_K)[lane] = o;
        return;
    }
    __shared__ int sh_hist[256], sh_scan[256], sh_cur[256];
    int t = threadIdx.x;
    sh_hist[t] = 0;
    __syncthreads();
    for (int i = t; i < B_N; i += 256) {
        int lb = lab[i];
        if (lb >= 0 && lb < NGENE) atomicAdd(&sh_hist[lb], 1);
    }
    __syncthreads();
    int v = sh_hist[t];
    sh_scan[t] = v;
    __syncthreads();
#pragma unroll
    for (int d = 1; d < 256; d <<= 1) {
        int x = (t >= d) ? sh_scan[t - d] : 0;
        __syncthreads();
        sh_scan[t] += x;
        __syncthreads();
    }
    int excl = sh_scan[t] - v;
    sh_cur[t] = excl;
    if (t < NGENE) { hist[t] = v; offs[t] = excl; }
    __syncthreads();
    for (int i = t; i < B_N; i += 256) {
        int lb = lab[i];
        if (lb >= 0 && lb < NGENE) {
            int pos = atomicAdd(&sh_cur[lb], 1);
            sorted[pos] = i;
        }
    }
}

// asm-pinned A-fragment loads (compiler cannot rematerialize or sink)
#define GLOAD8(arr, vo) do {                                                                   \
    asm volatile("global_load_dwordx4 %0, %1, %2 offset:0"   : "=v"(arr[0]) : "v"(vo), "s"(fb)); \
    asm volatile("global_load_dwordx4 %0, %1, %2 offset:64"  : "=v"(arr[1]) : "v"(vo), "s"(fb)); \
    asm volatile("global_load_dwordx4 %0, %1, %2 offset:128" : "=v"(arr[2]) : "v"(vo), "s"(fb)); \
    asm volatile("global_load_dwordx4 %0, %1, %2 offset:192" : "=v"(arr[3]) : "v"(vo), "s"(fb)); \
    asm volatile("global_load_dwordx4 %0, %1, %2 offset:256" : "=v"(arr[4]) : "v"(vo), "s"(fb)); \
    asm volatile("global_load_dwordx4 %0, %1, %2 offset:320" : "=v"(arr[5]) : "v"(vo), "s"(fb)); \
    asm volatile("global_load_dwordx4 %0, %1, %2 offset:384" : "=v"(arr[6]) : "v"(vo), "s"(fb)); \
    asm volatile("global_load_dwordx4 %0, %1, %2 offset:448" : "=v"(arr[7]) : "v"(vo), "s"(fb)); \
} while (0)

// async global->LDS, 16B per lane, zero VGPR result cost
#define GL_LDS16(gp, lp)                                                          \
    __builtin_amdgcn_global_load_lds(                                             \
        (const __attribute__((address_space(1))) unsigned int*)(gp),              \
        (__attribute__((address_space(3))) unsigned int*)(lp), 16, 0, 0)

#define Z4 ((f32x4){0.f, 0.f, 0.f, 0.f})
#define MFMA(A, B, C) __builtin_amdgcn_mfma_f32_16x16x32_bf16(A, B, C, 0, 0, 0)

#define EPI(AC, LS, CS) do {                                    \
    _Pragma("unroll")                                           \
    for (int r = 0; r < 4; ++r) {                               \
        float av = AC[r];                                       \
        LS[r] += __expf(2.0f * av);                             \
        CS += fmaxf(av - 0.05f, 0.f);                           \
    }                                                           \
} while (0)

#define WAIT_VM(n) do { asm volatile("s_waitcnt vmcnt(" #n ")" ::: "memory"); \
                        __builtin_amdgcn_sched_barrier(0); } while (0)

#define WAIT_LGKM0 do { asm volatile("s_waitcnt lgkmcnt(0)" ::: "memory"); \
                        __builtin_amdgcn_sched_barrier(0); } while (0)

// stage 16-col (8KB) tile t into this wave's LDS buffer at byte offset BOFF
#define STAGE_W(BOFF, T) do {                                                      \
    const char* gt = gw + (unsigned)(T) * 8192u;                                   \
    _Pragma("unroll")                                                              \
    for (int q = 0; q < 8; ++q)                                                    \
        GL_LDS16(gt + sv[q], smem_c + wbase + (BOFF) + q * 1024u);                 \
} while (0)

// ---- kernel 2: fused pairwise pass, BARRIER-FREE self-paced waves ----
// block = 4 waves x 64 rows; each wave owns a private 16KB LDS dbuf and stages its
// own 16-col B tiles (32 steps over the 512-col window). Sync = counted vmcnt only.
__global__ __launch_bounds__(256, 2) void k_pairwise(const unsigned short* __restrict__ fnbf,
                                                     float* __restrict__ l_part,
                                                     float* __restrict__ cross_part) {
    __shared__ __align__(16) char smem_c[65536];   // 4 waves x (2 x 8KB dbuf)
    __shared__ float shc[4];

    int tid = threadIdx.x;
    int wave = tid >> 6, lane = tid & 63;
    int g16 = lane >> 4, l16 = lane & 15;
    int l7 = l16 & 7;
    int rg = blockIdx.x, cwin = blockIdx.y;
    int r0 = rg * 256 + wave * 64;
    const unsigned short* fb = fnbf;
    unsigned wbase = (unsigned)wave * 16384u;

    // A fragments pinned: 4 row-tiles x 8 k-slices = 128 VGPRs
    bf16x8 a0[8], a1[8], a2[8], a3[8];
    unsigned voa = (unsigned)(r0 + l16) * 512u + (unsigned)g16 * 16u;
    GLOAD8(a0, voa); voa += 8192u;
    GLOAD8(a1, voa); voa += 8192u;
    GLOAD8(a2, voa); voa += 8192u;
    GLOAD8(a3, voa);

    // per-wave staging addresses: tile = 16 cols x 512B; LDS slot f = col*32 + s
    // holds source chunk s ^ (col&7) (inverse swizzle on source, linear dest).
    // 8 issues/wave/tile: f = q*64 + lane.
    const char* gw = (const char*)fnbf + (size_t)cwin * 262144u;
    unsigned sv[8];
#pragma unroll
    for (int q = 0; q < 8; ++q) {
        int f = q * 64 + lane;
        int col = f >> 5;
        sv[q] = (unsigned)(col * 512 + (((lane & 31) ^ (col & 7)) << 4));
    }

    // prologue: stage tiles 0,1 into buf0,buf1; wait A (32 oldest of 48)
    STAGE_W(0u, 0);
    STAGE_W(8192u, 1);
    WAIT_VM(16);

    float lsum[4][4] = {};
    float cs0 = 0.f, cs1 = 0.f, cs2 = 0.f, cs3 = 0.f;
    int vb = l16 * 512;

#pragma unroll 1
    for (int st = 0; st < 32; ++st) {
        if (st < 31) { WAIT_VM(8); }    // tile st retired (st+1's 8 in flight)
        else         { WAIT_VM(0); }    // last tile

        const char* base = smem_c + wbase + (unsigned)((st & 1) << 13);
        f32x4 acc0 = Z4, acc1 = Z4, acc2 = Z4, acc3 = Z4;
#pragma unroll
        for (int ks = 0; ks < 8; ++ks) {
            // chunk (ks*4+g16) of col l16 stored at slot ((ks*4+g16) ^ l7)
            const char* p = base + (unsigned)(vb + ((((ks << 2) | g16) ^ l7) << 4));
            bf16x8 bv = *(const bf16x8*)p;
            acc0 = MFMA(a0[ks], bv, acc0);
            acc1 = MFMA(a1[ks], bv, acc1);
            acc2 = MFMA(a2[ks], bv, acc2);
            acc3 = MFMA(a3[ks], bv, acc3);
        }
        EPI(acc0, lsum[0], cs0); EPI(acc1, lsum[1], cs1);
        EPI(acc2, lsum[2], cs2); EPI(acc3, lsum[3], cs3);

        if (st < 30) {
            WAIT_LGKM0;   // this wave's ds_reads of buf[st&1] retired -> safe to restage
            STAGE_W((unsigned)((st & 1) << 13), st + 2);
        }
    }

    // reduce exp-sums across the 16 lanes sharing each output row
#pragma unroll
    for (int t = 0; t < 4; ++t)
#pragma unroll
        for (int r = 0; r < 4; ++r) {
            float v = lsum[t][r];
            v += __shfl_xor(v, 1); v += __shfl_xor(v, 2);
            v += __shfl_xor(v, 4); v += __shfl_xor(v, 8);
            if (l16 == 0)
                l_part[(size_t)cwin * B_N + r0 + t * 16 + g16 * 4 + r] = v;
        }

    // block-reduce half-relu sum
    float c = (cs0 + cs1) + (cs2 + cs3);
#pragma unroll
    for (int m = 1; m < 64; m <<= 1) c += __shfl_xor(c, m);
    if (lane == 0) shc[wave] = c;
    __syncthreads();
    if (tid == 0)
        cross_part[cwin * 32 + rg] = shc[0] + shc[1] + shc[2] + shc[3];
}

// full-row dot from global (fallback path only; 32 x 16B = 512B per row)
__device__ __forceinline__ float dot_g(const uint4* __restrict__ fu, int i, int j) {
    const uint4* pa = fu + (size_t)i * 32;
    const uint4* pb = fu + (size_t)j * 32;
    float d = 0.f;
#pragma unroll
    for (int k = 0; k < 32; ++k) {
        uint4 ua = pa[k], ub = pb[k];
        d = fmaf(bf2f_lo(ua.x), bf2f_lo(ub.x), d);
        d = fmaf(bf2f_hi(ua.x), bf2f_hi(ub.x), d);
        d = fmaf(bf2f_lo(ua.y), bf2f_lo(ub.y), d);
        d = fmaf(bf2f_hi(ua.y), bf2f_hi(ub.y), d);
        d = fmaf(bf2f_lo(ua.z), bf2f_lo(ub.z), d);
        d = fmaf(bf2f_hi(ua.z), bf2f_hi(ub.z), d);
        d = fmaf(bf2f_lo(ua.w), bf2f_lo(ub.w), d);
        d = fmaf(bf2f_hi(ua.w), bf2f_hi(ub.w), d);
    }
    return d;
}

// ---- kernel 3: per-gene Gram matrix via MFMA + corrections + within loss ----
__global__ __launch_bounds__(256) void k_within(const unsigned short* __restrict__ fnbf,
                                                const int* __restrict__ hist,
                                                const int* __restrict__ offs,
                                                const int* __restrict__ sorted,
                                                const float* __restrict__ l_part,
                                                float* __restrict__ within_part,
                                                float* __restrict__ cross_corr) {
    int g = blockIdx.x;
    int n = hist[g], start = offs[g];
    int t = threadIdx.x;
    int wave = t >> 6, lane = t & 63;
    int g16 = lane >> 4, l16 = lane & 15;

    __shared__ float sim[128 * 130];   // sim[i][j] at i*130+j (pad -> 2-way banks)
    __shared__ int   rid[MAXN];
    __shared__ float slse[MAXN];
    __shared__ float red[256];

    for (int idx = t; idx < n; idx += 256) rid[idx] = sorted[start + idx];
    __syncthreads();

    float ccor = 0.f, wsum = 0.f;

    if (n <= 128) {
        int NT = (n + 15) >> 4;
        const bf16x8* fv = reinterpret_cast<const bf16x8*>(fnbf);
        for (int tile = wave; tile < NT * NT; tile += 4) {
            int ti = tile / NT, tj = tile - ti * NT;
            int ia = ti * 16 + l16;
            int ib = tj * 16 + l16;
            int ra = rid[ia < n ? ia : (n - 1)];
            int rb = rid[ib < n ? ib : (n - 1)];
            f32x4 acc = Z4;
#pragma unroll
            for (int ks = 0; ks < 8; ++ks) {
                bf16x8 av = fv[(size_t)ra * 32 + ks * 4 + g16];
                bf16x8 bv = fv[(size_t)rb * 32 + ks * 4 + g16];
                acc = MFMA(av, bv, acc);
            }
            int si = ti * 16 + g16 * 4;
            int sj = tj * 16 + l16;
#pragma unroll
            for (int r = 0; r < 4; ++r)
                sim[(si + r) * 130 + sj] = acc[r];
        }
        __syncthreads();

        for (int i = t; i < n; i += 256) {
            float raw = 0.f;
#pragma unroll
            for (int k = 0; k < 16; ++k) raw += l_part[(size_t)k * B_N + rid[i]];
            const float* srow = &sim[i * 130];
            float esum = 0.f;
            for (int j = 0; j < n; ++j) {
                float s = 2.0f * srow[j];
                esum += __expf(s);
                ccor += fmaxf(s - 0.1f, 0.f);
            }
            slse[i] = __logf(raw - esum);
        }
        __syncthreads();

        int nn = n * n;
        for (int p = t; p < nn; p += 256) {
            int i = p / n, j = p - i * n;
            if (j <= i) continue;
            float s = 2.0f * sim[i * 130 + j];
            int ai = (rid[i] < rid[j]) ? i : j;
            float x = slse[ai] - s;
            wsum += fmaxf(x, 0.f) + log1pf(__expf(-fabsf(x)));
        }
    } else {
        const uint4* fu = reinterpret_cast<const uint4*>(fnbf);
        for (int i = t; i < n; i += 256) {
            float raw = 0.f;
#pragma unroll
            for (int k = 0; k < 16; ++k) raw += l_part[(size_t)k * B_N + rid[i]];
            float esum = 0.f;
            for (int j = 0; j < n; ++j) {
                float s = 2.0f * dot_g(fu, rid[i], rid[j]);
                esum += __expf(s);
                ccor += fmaxf(s - 0.1f, 0.f);
            }
            slse[i] = __logf(raw - esum);
        }
        __syncthreads();
        int nn = n * n;
        for (int p = t; p < nn; p += 256) {
            int i = p / n, j = p - i * n;
            if (j <= i) continue;
            float s = 2.0f * dot_g(fu, rid[i], rid[j]);
            int ai = (rid[i] < rid[j]) ? i : j;
            float x = slse[ai] - s;
            wsum += fmaxf(x, 0.f) + log1pf(__expf(-fabsf(x)));
        }
    }

    red[t] = wsum;
    __syncthreads();
#pragma unroll
    for (int d2 = 128; d2 > 0; d2 >>= 1) {
        if (t < d2) red[t] += red[t + d2];
        __syncthreads();
    }
    if (t == 0) within_part[g] = red[0];
    __syncthreads();
    red[t] = ccor;
    __syncthreads();
#pragma unroll
    for (int d2 = 128; d2 > 0; d2 >>= 1) {
        if (t < d2) red[t] += red[t + d2];
        __syncthreads();
    }
    if (t == 0) cross_corr[g] = red[0];
}

// ---- kernel 4: final reduction + outputs ----
__global__ __launch_bounds__(256) void k_finalize(const float* __restrict__ cross_part,
                                                  const float* __restrict__ within_part,
                                                  const float* __restrict__ cross_corr,
                                                  const int* __restrict__ hist,
                                                  float* __restrict__ out) {
    __shared__ float shc[256];
    __shared__ float shw[256];
    __shared__ float shk[256];
    __shared__ long long shs[256];
    int t = threadIdx.x;
    float cs = 0.f;
    for (int i = t; i < 512; i += 256) cs += cross_part[i];
    float wv = 0.f, cc = 0.f;
    long long s2 = 0;
    if (t < NGENE) {
        wv = within_part[t];
        cc = cross_corr[t];
        long long h = hist[t];
        s2 = h * h;
    }
    shc[t] = cs; shw[t] = wv; shk[t] = cc; shs[t] = s2;
    __syncthreads();
#pragma unroll
    for (int d = 128; d > 0; d >>= 1) {
        if (t < d) {
            shc[t] += shc[t + d]; shw[t] += shw[t + d];
            shk[t] += shk[t + d]; shs[t] += shs[t + d];
        }
        __syncthreads();
    }
    if (t == 0) {
        long long S  = shs[0];
        long long nw = S - (long long)B_N;
        long long nc = (long long)B_N * (long long)B_N - S;
        float cross_total = 2.0f * shc[0] - shk[0];   // csum was half-relu units
        float cross_loss = (nc > 0) ? (cross_total / (float)(nc > 1 ? nc : 1)) : 0.f;
        float within     = shw[0];
        out[0] = within + 0.5f * cross_loss;
        out[1] = within;
        out[2] = cross_loss;
        out[3] = (float)nw;
        out[4] = (float)nc;
    }
}

extern "C" void kernel_launch(void* const* d_in, const int* in_sizes, int n_in,
                              void* d_out, int out_size, void* d_ws, size_t ws_size,
                              hipStream_t stream) {
    const float* feat = (const float*)d_in[0];
    const int*   lab  = (const int*)d_in[1];
    float* out = (float*)d_out;
    char* ws = (char*)d_ws;

    unsigned short* fnbf = (unsigned short*)(ws + OFF_FNBF);
    float* l_part        = (float*)(ws + OFF_LPART);
    int*   hist          = (int*)(ws + OFF_HIST);
    int*   offs          = (int*)(ws + OFF_OFFS);
    int*   sorted        = (int*)(ws + OFF_SORTED);
    float* cross_part    = (float*)(ws + OFF_CROSSP);
    float* within_part   = (float*)(ws + OFF_WITHINP);
    float* cross_corr    = (float*)(ws + OFF_CCORR);

    k_np<<<2049, 256, 0, stream>>>(feat, lab, fnbf, hist, offs, sorted);
    k_pairwise<<<dim3(32, 16), 256, 0, stream>>>(fnbf, l_part, cross_part);
    k_within<<<NGENE, 256, 0, stream>>>(fnbf, hist, offs, sorted, l_part, within_part, cross_corr);
    k_finalize<<<1, 256, 0, stream>>>(cross_part, within_part, cross_corr, hist, out);
}